// Round 13
// baseline (555.481 us; speedup 1.0000x reference)
//
#include <hip/hip_runtime.h>

// B=65536, Q=128, S=8, U=32
// R13: ABLATION ROUND. 4 two-pass probe kernels (asm-sunk, no d_out writes)
// + the real kernel last. Probes isolate: V1 epilogue VALU, V2 weight loads,
// V3 x-staging/barriers. Decision: biggest dropper is R14's target.
#define Q    128
#define S    8
#define U    32
#define QCH  16
#define NCH  (Q / QCH)
#define ROWS 64
#define WQ   4
#define RSTRIDE 272
#define ZOFF (ROWS * RSTRIDE)

typedef __attribute__((ext_vector_type(8)))  __bf16 bf16x8;
typedef __attribute__((ext_vector_type(16))) float  f32x16;
typedef __attribute__((ext_vector_type(2)))  float  f32x2;

__device__ inline unsigned short f2bf(float f) {
    unsigned int u = __float_as_uint(f);
    u += 0x7FFF + ((u >> 16) & 1);
    return (unsigned short)(u >> 16);
}

__device__ inline unsigned int cvt_pk_bf16(float lo, float hi) {
    unsigned int r;
    asm("v_cvt_pk_bf16_f32 %0, %1, %2" : "=v"(r) : "v"(lo), "v"(hi));
    return r;
}

__device__ __forceinline__ void sinkf(float v) { asm volatile("" :: "v"(v)); }

// ---- prep: W1T[q][u][s] bf16 ; b1F=(b1+1), w2F in C-reg order ; b2F=b2-sum(W2)
__global__ void prep_kernel(const float* __restrict__ W1, const float* __restrict__ b1,
                            const float* __restrict__ W2, const float* __restrict__ b2,
                            unsigned short* __restrict__ W1T,
                            float* __restrict__ b1F, float* __restrict__ w2F,
                            float* __restrict__ b2F)
{
    const int q = blockIdx.x, t = threadIdx.x;
    const int u = t & 31, s = t >> 5;
    W1T[(q * 32 + u) * 8 + s] = f2bf(W1[(q * 8 + s) * 32 + u]);
    if (t < 32) {
        int reg = t & 15, hh = t >> 4;
        int uu  = (reg & 3) + 8 * (reg >> 2) + 4 * hh;
        b1F[(q * 2 + hh) * 16 + reg] = b1[q * 32 + uu] + 1.0f;
        w2F[(q * 2 + hh) * 16 + reg] = W2[q * 32 + uu];
    }
    if (t == 0) {
        float sw = 0.f;
        for (int uu = 0; uu < 32; ++uu) sw += W2[q * 32 + uu];
        b2F[q] = b2[q] - sw;
    }
}

// V: 0=full  1=no-epilogue  2=no-weight-loads  3=no-staging
template<int V, int PASSES, bool STORE>
__global__ __launch_bounds__(256, 4)
void divenc_v(const float* __restrict__ x,
              const unsigned short* __restrict__ W1T,
              const float* __restrict__ b1F,
              const float* __restrict__ w2F,
              const float* __restrict__ b2F,
              float* __restrict__ out, int B)
{
    __shared__ __align__(16) unsigned char xs[ROWS * RSTRIDE + 16];

    const int t     = threadIdx.x;
    const int lane  = t & 63;
    const int wv    = __builtin_amdgcn_readfirstlane(t >> 6);
    const int rbase = blockIdx.x * ROWS;
    const int rmax  = B - 1;
    const int bl    = lane & 31;
    const int h     = lane >> 5;
    const bool lo   = (lane < 32);

    if (t == 0) *(uint4*)(xs + ZOFF) = uint4{0, 0, 0, 0};   // keeps LDS alloc in V3

    const f32x2 l2e2  = 1.44269504088896f;
    const f32x2 nl2e2 = -1.44269504088896f;
    const f32x2 zero2 = 0.0f;
    const uint4 kone  = uint4{0x3f803f80u, 0x3f803f80u, 0x3f803f80u, 0x3f803f80u};

    #pragma unroll 1
    for (int pass = 0; pass < PASSES; ++pass) {
    #pragma unroll 1
    for (int ch = 0; ch < NCH; ++ch) {
        const int q0 = ch * QCH;
        if constexpr (V != 3) {
            __syncthreads();
            #pragma unroll
            for (int k = 0; k < 4; ++k) {
                int idx = t + k * 256;
                int row = idx >> 4, qr = idx & 15;
                int r = rbase + row; if (r > rmax) r = rmax;
                const float4* p = (const float4*)(x + (size_t)r * (Q * S)
                                                    + (size_t)(q0 + qr) * S);
                float4 a = p[0], b = p[1];
                uint4 w;
                w.x = cvt_pk_bf16(a.x, a.y); w.y = cvt_pk_bf16(a.z, a.w);
                w.z = cvt_pk_bf16(b.x, b.y); w.w = cvt_pk_bf16(b.z, b.w);
                *(uint4*)(xs + row * RSTRIDE + qr * 16) = w;
            }
            __syncthreads();
        }

        #pragma unroll 1
        for (int qi = 0; qi < WQ; ++qi) {
            const int qr = wv * WQ + qi;
            const int q  = q0 + qr;

            uint4 bx0, bx1;
            if constexpr (V != 3) {
                const int xoff = bl * RSTRIDE + qr * 16;
                bx0 = *(const uint4*)(xs + (lo ? xoff                : ZOFF));
                bx1 = *(const uint4*)(xs + (lo ? xoff + 32 * RSTRIDE : ZOFF));
            } else {
                bx0 = kone; bx1 = kone;
            }

            uint4 ax; f32x16 cin;
            if constexpr (V != 2) {
                ax  = *(const uint4*)(W1T + ((size_t)q * 32 + bl) * 8);
                cin = *(const f32x16*)(b1F + ((size_t)q * 2 + h) * 16);
            } else {
                ax = kone; cin = 0.0f;
            }

            f32x16 cc0 = __builtin_amdgcn_mfma_f32_32x32x16_bf16(
                __builtin_bit_cast(bf16x8, ax), __builtin_bit_cast(bf16x8, bx0),
                cin, 0, 0, 0);
            f32x16 cc1 = __builtin_amdgcn_mfma_f32_32x32x16_bf16(
                __builtin_bit_cast(bf16x8, ax), __builtin_bit_cast(bf16x8, bx1),
                cin, 0, 0, 0);

            f32x16 wr; float b2v;
            if constexpr (V != 2) {
                wr  = *(const f32x16*)(w2F + ((size_t)q * 2 + h) * 16);
                b2v = b2F[q];
            } else {
                wr = 1.0f; b2v = 0.0f;
            }

            if constexpr (V == 1) {
                // keep MFMAs + all 4 dwordx4 of wr + b2v live, drop epilogue VALU
                sinkf(cc0[0]); sinkf(cc1[0]);
                sinkf(wr[0]); sinkf(wr[4]); sinkf(wr[8]); sinkf(wr[12]);
                sinkf(b2v);
            } else {
#define EL2(CC, J, ACC) {                                                            \
        f32x2 v_; v_.x = CC[2*(J)]; v_.y = CC[2*(J)+1];                              \
        f32x2 w2v; w2v.x = wr[2*(J)]; w2v.y = wr[2*(J)+1];                           \
        f32x2 f_ = __builtin_elementwise_fma(v_, l2e2, nl2e2);                       \
        f_ = __builtin_elementwise_min(f_, zero2);                                   \
        f32x2 e_; e_.x = __builtin_amdgcn_exp2f(f_.x);                               \
        e_.y = __builtin_amdgcn_exp2f(f_.y);                                         \
        f32x2 r_ = __builtin_elementwise_max(v_, e_);                                \
        ACC = __builtin_elementwise_fma(r_, w2v, ACC); }

                f32x2 acc0 = 0.0f, acc1 = 0.0f;
                EL2(cc0, 0, acc0) EL2(cc0, 1, acc0) EL2(cc0, 2, acc0) EL2(cc0, 3, acc0)
                EL2(cc0, 4, acc0) EL2(cc0, 5, acc0) EL2(cc0, 6, acc0) EL2(cc0, 7, acc0)
                EL2(cc1, 0, acc1) EL2(cc1, 1, acc1) EL2(cc1, 2, acc1) EL2(cc1, 3, acc1)
                EL2(cc1, 4, acc1) EL2(cc1, 5, acc1) EL2(cc1, 6, acc1) EL2(cc1, 7, acc1)
#undef EL2
                float a0 = acc0.x + acc0.y;
                float a1 = acc1.x + acc1.y;
                a0 += __shfl_xor(a0, 32);
                a1 += __shfl_xor(a1, 32);
                if constexpr (STORE) {
                    const int r0 = rbase + bl, r1 = r0 + 32;
                    if (lo && r0 < B) out[(size_t)r0 * Q + q] = a0 + b2v;
                    if (lo && r1 < B) out[(size_t)r1 * Q + q] = a1 + b2v;
                } else {
                    sinkf(a0 + b2v); sinkf(a1 + b2v);
                }
            }
        }
    }
    }
}

extern "C" void kernel_launch(void* const* d_in, const int* in_sizes, int n_in,
                              void* d_out, int out_size, void* d_ws, size_t ws_size,
                              hipStream_t stream) {
    const float* x  = (const float*)d_in[0];
    const float* W1 = (const float*)d_in[1];
    const float* b1 = (const float*)d_in[2];
    const float* W2 = (const float*)d_in[3];
    const float* b2 = (const float*)d_in[4];
    float* out = (float*)d_out;

    unsigned short* W1T = (unsigned short*)d_ws;                 // 64 KB
    float*          b1F = (float*)((char*)d_ws + 65536);         // 16 KB
    float*          w2F = (float*)((char*)d_ws + 81920);         // 16 KB
    float*          b2F = (float*)((char*)d_ws + 98304);         // 512 B

    const int B = in_sizes[0] / (Q * S);
    const int nblocks = (B + ROWS - 1) / ROWS;

    hipLaunchKernelGGL(prep_kernel, dim3(Q), dim3(256), 0, stream,
                       W1, b1, W2, b2, W1T, b1F, w2F, b2F);

    // ---- probes (2-pass, sunk outputs; visible in rocprof top-5) ----
    hipLaunchKernelGGL((divenc_v<0, 2, false>), dim3(nblocks), dim3(256), 0, stream,
                       x, W1T, b1F, w2F, b2F, out, B);
    hipLaunchKernelGGL((divenc_v<1, 2, false>), dim3(nblocks), dim3(256), 0, stream,
                       x, W1T, b1F, w2F, b2F, out, B);
    hipLaunchKernelGGL((divenc_v<2, 2, false>), dim3(nblocks), dim3(256), 0, stream,
                       x, W1T, b1F, w2F, b2F, out, B);
    hipLaunchKernelGGL((divenc_v<3, 2, false>), dim3(nblocks), dim3(256), 0, stream,
                       x, W1T, b1F, w2F, b2F, out, B);

    // ---- real kernel (single pass, writes d_out) ----
    hipLaunchKernelGGL((divenc_v<0, 1, true>), dim3(nblocks), dim3(256), 0, stream,
                       x, W1T, b1F, w2F, b2F, out, B);
}

// Round 14
// 166.053 us; speedup vs baseline: 3.3452x; 3.3452x over previous
//
#include <hip/hip_runtime.h>

// B=65536, Q=128, S=8, U=32
// out[b,q] = b2[q] + sum_u elu(b1[q,u] + sum_s x[b,q,s]*W1[q,s,u]) * W2[q,u]
//
// R14: no-LDS no-barrier direct structure. x has ZERO reuse (each element
// feeds exactly one (b,q) fragment) -> LDS staging was pure overhead (guide
// CM#7). Each lane<32 loads its B-fragment rows directly from global; lanes
// >=32 read a prep-zeroed 8KB page (free K-padding). Waves free-run: no
// barriers, no staging registers. q = 4*qi + wv keeps concurrent waves on
// shared weight/x cache lines.
#define Q    128
#define S    8
#define U    32
#define ROWS 64

typedef __attribute__((ext_vector_type(8)))  __bf16 bf16x8;
typedef __attribute__((ext_vector_type(16))) float  f32x16;
typedef __attribute__((ext_vector_type(2)))  float  f32x2;

__device__ inline unsigned short f2bf(float f) {   // RTN f32->bf16 (prep only)
    unsigned int u = __float_as_uint(f);
    u += 0x7FFF + ((u >> 16) & 1);
    return (unsigned short)(u >> 16);
}

__device__ inline unsigned int cvt_pk_bf16(float lo, float hi) {
    unsigned int r;
    asm("v_cvt_pk_bf16_f32 %0, %1, %2" : "=v"(r) : "v"(lo), "v"(hi));
    return r;
}

// ---- prep: W1T[q][u][s] bf16 ; b1F=(b1+1), w2F in C-reg order ;
//      b2F=b2-sum(W2) ; zero-page (8KB) for hi-lane B-fragment reads ----
__global__ void prep_kernel(const float* __restrict__ W1, const float* __restrict__ b1,
                            const float* __restrict__ W2, const float* __restrict__ b2,
                            unsigned short* __restrict__ W1T,
                            float* __restrict__ b1F, float* __restrict__ w2F,
                            float* __restrict__ b2F, float* __restrict__ zpg)
{
    const int q = blockIdx.x, t = threadIdx.x;     // 128 blocks x 256 threads
    const int u = t & 31, s = t >> 5;
    W1T[(q * 32 + u) * 8 + s] = f2bf(W1[(q * 8 + s) * 32 + u]);
    if (t < 32) {
        int reg = t & 15, hh = t >> 4;
        int uu  = (reg & 3) + 8 * (reg >> 2) + 4 * hh;   // verified C/D row map
        b1F[(q * 2 + hh) * 16 + reg] = b1[q * 32 + uu] + 1.0f;
        w2F[(q * 2 + hh) * 16 + reg] = W2[q * 32 + uu];
    }
    if (t == 0) {
        float sw = 0.f;
        for (int uu = 0; uu < 32; ++uu) sw += W2[q * 32 + uu];
        b2F[q] = b2[q] - sw;
    }
    if (q == 0) {                                  // zero the 8KB pad page
        float4 z{0.f, 0.f, 0.f, 0.f};
        ((float4*)zpg)[t * 2]     = z;
        ((float4*)zpg)[t * 2 + 1] = z;
    }
}

__global__ __launch_bounds__(256, 4)   // VGPR budget 128
void divenc_direct(const float* __restrict__ x,
                   const unsigned short* __restrict__ W1T,
                   const float* __restrict__ b1F,
                   const float* __restrict__ w2F,
                   const float* __restrict__ b2F,
                   const float* __restrict__ zpg,
                   float* __restrict__ out, int B)
{
    const int t     = threadIdx.x;
    const int lane  = t & 63;
    const int wv    = __builtin_amdgcn_readfirstlane(t >> 6);  // 0..3
    const int bl    = lane & 31;             // b-row (tile) / u (A row)
    const int h     = lane >> 5;
    const bool lo   = (lane < 32);
    const int rbase = blockIdx.x * ROWS;

    int r0 = rbase + bl;      if (r0 > B - 1) r0 = B - 1;   // safety clamp
    int r1 = r0 + 32;         int r1c = (r1 > B - 1) ? (B - 1) : r1;

    // lanes>=32 point at the zeroed page: their fragment = 0 = K-padding
    const float4* xp0 = lo ? (const float4*)(x + (size_t)r0  * (Q * S)) : (const float4*)zpg;
    const float4* xp1 = lo ? (const float4*)(x + (size_t)r1c * (Q * S)) : (const float4*)zpg;

    const f32x2 l2e2  = 1.44269504088896f;
    const f32x2 nl2e2 = -1.44269504088896f;
    const f32x2 zero2 = 0.0f;

    #pragma unroll 2
    for (int qi = 0; qi < Q / 4; ++qi) {
        const int q = qi * 4 + wv;           // wave-uniform

        // ---- B-fragments: 2 rows x 32B direct from global (L2-served) ----
        float4 a0 = xp0[q * 2], a1 = xp0[q * 2 + 1];
        float4 c0 = xp1[q * 2], c1 = xp1[q * 2 + 1];
        uint4 bx0, bx1;
        bx0.x = cvt_pk_bf16(a0.x, a0.y); bx0.y = cvt_pk_bf16(a0.z, a0.w);
        bx0.z = cvt_pk_bf16(a1.x, a1.y); bx0.w = cvt_pk_bf16(a1.z, a1.w);
        bx1.x = cvt_pk_bf16(c0.x, c0.y); bx1.y = cvt_pk_bf16(c0.z, c0.w);
        bx1.z = cvt_pk_bf16(c1.x, c1.y); bx1.w = cvt_pk_bf16(c1.z, c1.w);

        // ---- A-frag + C-in (L1/L2-resident weights) ----
        uint4  ax  = *(const uint4*)(W1T + ((size_t)q * 32 + bl) * 8);
        f32x16 cin = *(const f32x16*)(b1F + ((size_t)q * 2 + h) * 16);

        f32x16 cc0 = __builtin_amdgcn_mfma_f32_32x32x16_bf16(
            __builtin_bit_cast(bf16x8, ax), __builtin_bit_cast(bf16x8, bx0),
            cin, 0, 0, 0);
        f32x16 cc1 = __builtin_amdgcn_mfma_f32_32x32x16_bf16(
            __builtin_bit_cast(bf16x8, ax), __builtin_bit_cast(bf16x8, bx1),
            cin, 0, 0, 0);

        f32x16 wr  = *(const f32x16*)(w2F + ((size_t)q * 2 + h) * 16);
        const float b2v = b2F[q];

        // ---- 5-op ELU+1: r = max(v', exp2(min(v'*log2e - log2e, 0))) ----
#define EL2(CC, J, ACC) {                                                            \
        f32x2 v_; v_.x = CC[2*(J)]; v_.y = CC[2*(J)+1];                              \
        f32x2 w2v; w2v.x = wr[2*(J)]; w2v.y = wr[2*(J)+1];                           \
        f32x2 f_ = __builtin_elementwise_fma(v_, l2e2, nl2e2);                       \
        f_ = __builtin_elementwise_min(f_, zero2);                                   \
        f32x2 e_; e_.x = __builtin_amdgcn_exp2f(f_.x);                               \
        e_.y = __builtin_amdgcn_exp2f(f_.y);                                         \
        f32x2 r_ = __builtin_elementwise_max(v_, e_);                                \
        ACC = __builtin_elementwise_fma(r_, w2v, ACC); }

        f32x2 acc0 = 0.0f, acc1 = 0.0f;
        EL2(cc0, 0, acc0) EL2(cc0, 1, acc0) EL2(cc0, 2, acc0) EL2(cc0, 3, acc0)
        EL2(cc0, 4, acc0) EL2(cc0, 5, acc0) EL2(cc0, 6, acc0) EL2(cc0, 7, acc0)
        EL2(cc1, 0, acc1) EL2(cc1, 1, acc1) EL2(cc1, 2, acc1) EL2(cc1, 3, acc1)
        EL2(cc1, 4, acc1) EL2(cc1, 5, acc1) EL2(cc1, 6, acc1) EL2(cc1, 7, acc1)
#undef EL2

        float o0 = acc0.x + acc0.y;
        float o1 = acc1.x + acc1.y;
        o0 += __shfl_xor(o0, 32);            // combine u-halves
        o1 += __shfl_xor(o1, 32);

        if (lo) {
            out[(size_t)r0 * Q + q] = o0 + b2v;
            if (r1 < B) out[(size_t)r1 * Q + q] = o1 + b2v;
        }
    }
}

extern "C" void kernel_launch(void* const* d_in, const int* in_sizes, int n_in,
                              void* d_out, int out_size, void* d_ws, size_t ws_size,
                              hipStream_t stream) {
    const float* x  = (const float*)d_in[0];
    const float* W1 = (const float*)d_in[1];
    const float* b1 = (const float*)d_in[2];
    const float* W2 = (const float*)d_in[3];
    const float* b2 = (const float*)d_in[4];
    float* out = (float*)d_out;

    unsigned short* W1T = (unsigned short*)d_ws;                 // 64 KB
    float*          b1F = (float*)((char*)d_ws + 65536);         // 16 KB
    float*          w2F = (float*)((char*)d_ws + 81920);         // 16 KB
    float*          b2F = (float*)((char*)d_ws + 98304);         // 512 B
    float*          zpg = (float*)((char*)d_ws + 98816);         // 8 KB zeros

    const int B = in_sizes[0] / (Q * S);

    hipLaunchKernelGGL(prep_kernel, dim3(Q), dim3(256), 0, stream,
                       W1, b1, W2, b2, W1T, b1F, w2F, b2F, zpg);
    hipLaunchKernelGGL(divenc_direct, dim3((B + ROWS - 1) / ROWS), dim3(256), 0, stream,
                       x, W1T, b1F, w2F, b2F, zpg, out, B);
}

// Round 15
// 137.440 us; speedup vs baseline: 4.0416x; 1.2082x over previous
//
#include <hip/hip_runtime.h>

// B=65536, Q=128, S=8, U=32
// out[b,q] = b2[q] + sum_u elu(b1[q,u] + sum_s x[b,q,s]*W1[q,s,u]) * W2[q,u]
//
// R15: global_load_lds DMA staging (guide Common-mistake #1). R13/R14 showed
// the kernel is VALU-issue-bound on data MOVEMENT (~11 of 13.6 instr/output
// were staging). DMA moves x HBM->LDS with ZERO VALU/VGPR cost; per-lane
// global source addresses realize the layout permutation (m173 pattern);
// consume side converts f32->bf16 with cvt_pk. One barrier per chunk,
// double-buffered: DMA(ch+1) flies under consume(ch).
#define Q    128
#define S    8
#define U    32
#define QCH  16
#define NCH  8
#define ROWS 64
#define WQ   4
#define XBUF 32768              // 16q * 64row * 32B f32 per chunk buffer
#define ZOFF (2 * XBUF)         // 16B zero page (hi-lane K-padding)

typedef __attribute__((ext_vector_type(8)))  __bf16 bf16x8;
typedef __attribute__((ext_vector_type(16))) float  f32x16;
typedef __attribute__((ext_vector_type(2)))  float  f32x2;

__device__ inline unsigned short f2bf(float f) {   // RTN f32->bf16 (prep only)
    unsigned int u = __float_as_uint(f);
    u += 0x7FFF + ((u >> 16) & 1);
    return (unsigned short)(u >> 16);
}

__device__ inline unsigned int cvt_pk_bf16(float lo, float hi) {
    unsigned int r;
    asm("v_cvt_pk_bf16_f32 %0, %1, %2" : "=v"(r) : "v"(lo), "v"(hi));
    return r;
}

// ---- prep: W1T[q][u][s] bf16 ; b1F=(b1+1), w2F in C-reg order ; b2F=b2-sum(W2)
__global__ void prep_kernel(const float* __restrict__ W1, const float* __restrict__ b1,
                            const float* __restrict__ W2, const float* __restrict__ b2,
                            unsigned short* __restrict__ W1T,
                            float* __restrict__ b1F, float* __restrict__ w2F,
                            float* __restrict__ b2F)
{
    const int q = blockIdx.x, t = threadIdx.x;     // 128 blocks x 256 threads
    const int u = t & 31, s = t >> 5;
    W1T[(q * 32 + u) * 8 + s] = f2bf(W1[(q * 8 + s) * 32 + u]);
    if (t < 32) {
        int reg = t & 15, hh = t >> 4;
        int uu  = (reg & 3) + 8 * (reg >> 2) + 4 * hh;   // verified C/D row map
        b1F[(q * 2 + hh) * 16 + reg] = b1[q * 32 + uu] + 1.0f;
        w2F[(q * 2 + hh) * 16 + reg] = W2[q * 32 + uu];
    }
    if (t == 0) {
        float sw = 0.f;
        for (int uu = 0; uu < 32; ++uu) sw += W2[q * 32 + uu];
        b2F[q] = b2[q] - sw;
    }
}

// 8 global_load_lds (width 16) per wave per chunk. dst wave-uniform; src per-lane.
__device__ __forceinline__ void dma_chunk(const char* src, unsigned char* dst,
                                          const unsigned int* gofs) {
    #pragma unroll
    for (int w = 0; w < 8; ++w)
        __builtin_amdgcn_global_load_lds(
            (const __attribute__((address_space(1))) unsigned int*)(src + gofs[w]),
            (__attribute__((address_space(3))) unsigned int*)(dst + w * 1024),
            16, 0, 0);
}

__global__ __launch_bounds__(256, 2)   // VGPR budget 256; LDS caps 2 blocks/CU
void divenc_dma(const float* __restrict__ x,
                const unsigned short* __restrict__ W1T,
                const float* __restrict__ b1F,
                const float* __restrict__ w2F,
                const float* __restrict__ b2F,
                float* __restrict__ out, int B)
{
    __shared__ __align__(16) unsigned char xs[2 * XBUF + 16];  // ~64.02 KB

    const int t    = threadIdx.x;
    const int lane = t & 63;
    const int wv   = __builtin_amdgcn_readfirstlane(t >> 6);
    const int bl   = lane & 31;
    const int h    = lane >> 5;
    const bool lo  = (lane < 32);
    int rbase = blockIdx.x * ROWS;
    if (rbase > B - ROWS) rbase = B - ROWS;        // tail overlap (idempotent)

    if (t == 0) *(uint4*)(xs + ZOFF) = uint4{0, 0, 0, 0};

    // ---- per-lane DMA source offsets: decode slot -> (qr,row,half) ----
    // slot A = wv*8192 + w*1024 + lane*16 ; layout L(qr,row,hf) =
    // qr*2048 + row*32 + (hf ^ ((row>>2)&1))*16  (XOR -> <=2-way LDS banks)
    unsigned int gofs[8];
    #pragma unroll
    for (int w = 0; w < 8; ++w) {
        int A   = wv * 8192 + w * 1024 + lane * 16;
        int qr  = A >> 11;
        int rem = A & 2047;
        int row = rem >> 5;
        int hf  = ((rem >> 4) & 1) ^ ((row >> 2) & 1);
        gofs[w] = (unsigned int)(row * 4096 + qr * 32 + hf * 16);
    }
    const char* xblk = (const char*)x + (size_t)rbase * (Q * S * 4);

    const f32x2 l2e2  = 1.44269504088896f;
    const f32x2 nl2e2 = -1.44269504088896f;
    const f32x2 zero2 = 0.0f;

    dma_chunk(xblk, xs + wv * 8192, gofs);         // DMA(0) -> buf0

    #pragma unroll 1
    for (int ch = 0; ch < NCH; ++ch) {
        __syncthreads();                           // drains DMA(ch); buf ready
        if (ch + 1 < NCH)                          // DMA(ch+1) flies under consume
            dma_chunk(xblk + (ch + 1) * 512,
                      xs + ((ch + 1) & 1) * XBUF + wv * 8192, gofs);

        const int rbuf = (ch & 1) * XBUF;
        const int swz  = ((bl >> 2) & 1) << 4;

        #pragma unroll 2
        for (int qi = 0; qi < WQ; ++qi) {
            const int qr = wv * WQ + qi;           // uniform per wave
            const int q  = ch * QCH + qr;

            const int base0 = rbuf + qr * 2048 + bl * 32;
            // tile0 (row=bl) and tile1 (row=bl+32): same swz (bit3 of row>>2 drops)
            const float4 p00 = *(const float4*)(xs + (lo ? base0 + swz          : ZOFF));
            const float4 p01 = *(const float4*)(xs + (lo ? base0 + (16 ^ swz)   : ZOFF));
            const float4 p10 = *(const float4*)(xs + (lo ? base0 + 1024 + swz   : ZOFF));
            const float4 p11 = *(const float4*)(xs + (lo ? base0 + 1024 + (16 ^ swz) : ZOFF));

            uint4 bx0, bx1;
            bx0.x = cvt_pk_bf16(p00.x, p00.y); bx0.y = cvt_pk_bf16(p00.z, p00.w);
            bx0.z = cvt_pk_bf16(p01.x, p01.y); bx0.w = cvt_pk_bf16(p01.z, p01.w);
            bx1.x = cvt_pk_bf16(p10.x, p10.y); bx1.y = cvt_pk_bf16(p10.z, p10.w);
            bx1.z = cvt_pk_bf16(p11.x, p11.y); bx1.w = cvt_pk_bf16(p11.z, p11.w);

            uint4  ax  = *(const uint4*)(W1T + ((size_t)q * 32 + bl) * 8);
            f32x16 cin = *(const f32x16*)(b1F + ((size_t)q * 2 + h) * 16);

            f32x16 cc0 = __builtin_amdgcn_mfma_f32_32x32x16_bf16(
                __builtin_bit_cast(bf16x8, ax), __builtin_bit_cast(bf16x8, bx0),
                cin, 0, 0, 0);
            f32x16 cc1 = __builtin_amdgcn_mfma_f32_32x32x16_bf16(
                __builtin_bit_cast(bf16x8, ax), __builtin_bit_cast(bf16x8, bx1),
                cin, 0, 0, 0);

            f32x16 wr  = *(const f32x16*)(w2F + ((size_t)q * 2 + h) * 16);
            const float b2v = b2F[q];

            // ---- 5-op ELU+1: r = max(v', exp2(min(v'*log2e - log2e, 0))) ----
#define EL2(CC, J, ACC) {                                                            \
        f32x2 v_; v_.x = CC[2*(J)]; v_.y = CC[2*(J)+1];                              \
        f32x2 w2v; w2v.x = wr[2*(J)]; w2v.y = wr[2*(J)+1];                           \
        f32x2 f_ = __builtin_elementwise_fma(v_, l2e2, nl2e2);                       \
        f_ = __builtin_elementwise_min(f_, zero2);                                   \
        f32x2 e_; e_.x = __builtin_amdgcn_exp2f(f_.x);                               \
        e_.y = __builtin_amdgcn_exp2f(f_.y);                                         \
        f32x2 r_ = __builtin_elementwise_max(v_, e_);                                \
        ACC = __builtin_elementwise_fma(r_, w2v, ACC); }

            f32x2 acc0 = 0.0f, acc1 = 0.0f;
            EL2(cc0, 0, acc0) EL2(cc0, 1, acc0) EL2(cc0, 2, acc0) EL2(cc0, 3, acc0)
            EL2(cc0, 4, acc0) EL2(cc0, 5, acc0) EL2(cc0, 6, acc0) EL2(cc0, 7, acc0)
            EL2(cc1, 0, acc1) EL2(cc1, 1, acc1) EL2(cc1, 2, acc1) EL2(cc1, 3, acc1)
            EL2(cc1, 4, acc1) EL2(cc1, 5, acc1) EL2(cc1, 6, acc1) EL2(cc1, 7, acc1)
#undef EL2

            float a0 = acc0.x + acc0.y;
            float a1 = acc1.x + acc1.y;
            a0 += __shfl_xor(a0, 32);              // combine u-halves
            a1 += __shfl_xor(a1, 32);

            if (lo) {
                const int r0 = rbase + bl;
                out[(size_t)r0 * Q + q]        = a0 + b2v;
                out[(size_t)(r0 + 32) * Q + q] = a1 + b2v;
            }
        }
    }
}

extern "C" void kernel_launch(void* const* d_in, const int* in_sizes, int n_in,
                              void* d_out, int out_size, void* d_ws, size_t ws_size,
                              hipStream_t stream) {
    const float* x  = (const float*)d_in[0];
    const float* W1 = (const float*)d_in[1];
    const float* b1 = (const float*)d_in[2];
    const float* W2 = (const float*)d_in[3];
    const float* b2 = (const float*)d_in[4];
    float* out = (float*)d_out;

    unsigned short* W1T = (unsigned short*)d_ws;                 // 64 KB
    float*          b1F = (float*)((char*)d_ws + 65536);         // 16 KB
    float*          w2F = (float*)((char*)d_ws + 81920);         // 16 KB
    float*          b2F = (float*)((char*)d_ws + 98304);         // 512 B

    const int B = in_sizes[0] / (Q * S);

    hipLaunchKernelGGL(prep_kernel, dim3(Q), dim3(256), 0, stream,
                       W1, b1, W2, b2, W1T, b1F, w2F, b2F);
    hipLaunchKernelGGL(divenc_dma, dim3(B / ROWS), dim3(256), 0, stream,
                       x, W1T, b1F, w2F, b2F, out, B);
}